// Round 5
// baseline (182.381 us; speedup 1.0000x reference)
//
#include <hip/hip_runtime.h>

// Sparse 2-hop GCN slice: output depends only on h2[tgt], tgt = argmax(mut_mask).
// R5: head parallelized (16-block f1 with redundant u/W2/feat; 1-block f2/out),
// kh2 folded into head via linearity: h2 = (sum_b norm_b*relu(h1[s_b]+b1)) @ W2.
// h1 zero-init moved into kpassB (only ns*HID entries). 7 dispatches.

#define SCAP   512      // cap on |S1|; expected ~17
#define L1CAP  512      // cap on edges into tgt; expected ~17
#define L2CAP  16384    // cap on edges into S1; expected ~300
#define HID    256
#define INDIM  128

struct WsPtrs {
  int* cnt;                 // [0]=cntL1 [1]=cntS1 [2]=cntL2 [3]=is64 [4]=tgt
  float* deg;               // [N] lazily initialized
  int* slot;                // [N] -1 unknown, >=0 S1 slot, -2 transient, -3 deg-needed
  int* s1;                  // [SCAP]
  int* l1r; float* l1w;     // edges into tgt
  int* l2r; int* l2s; float* l2w; // edges into S1
  float* h1;                // [SCAP*HID]; first ns rows zeroed in kpassB
  float* f1;                // [512] head hidden
  int* wscol;               // [E] col as int32
};

// K1: slot=-1 (int4), argmax of one-hot mask (plain store), cnt, is64 detect
__global__ void kinit(WsPtrs w, const int* eiraw, const float* mask, int N, int E) {
  int g = blockIdx.x * blockDim.x + threadIdx.x;
  int gs = gridDim.x * blockDim.x;
  int nv = N >> 2;
  int4* s4 = (int4*)w.slot;
  int4 m1 = make_int4(-1, -1, -1, -1);
  for (int j = g; j < nv; j += gs) s4[j] = m1;
  for (int j = 4 * nv + g; j < N; j += gs) w.slot[j] = -1;
  const float4* m4 = (const float4*)mask;
  for (int j = g; j < nv; j += gs) {
    float4 v = m4[j];
    if (v.x > 0.f) w.cnt[4] = 4 * j;
    if (v.y > 0.f) w.cnt[4] = 4 * j + 1;
    if (v.z > 0.f) w.cnt[4] = 4 * j + 2;
    if (v.w > 0.f) w.cnt[4] = 4 * j + 3;
  }
  for (int j = 4 * nv + g; j < N; j += gs) if (mask[j] > 0.f) w.cnt[4] = j;
  if (g < 3) w.cnt[g] = 0;
  if (g == 3) {
    int is64 = 1;
    long step = E / 20; if (step < 1) step = 1;
    for (int j = 1; j <= 16; ++j) {
      long idx = (long)j * step; if (idx >= E) break;
      if (eiraw[2 * idx + 1] != 0) { is64 = 0; break; }  // ids < 2^31 -> hi word 0
    }
    w.cnt[3] = is64;
  }
}

__device__ __forceinline__ void reg_s1(WsPtrs& w, int r) {
  int old = atomicCAS(&w.slot[r], -1, -2);
  if (old == -1) {
    w.deg[r] = 1.0f;                       // lazy init, self-loop weight
    int idx = atomicAdd(&w.cnt[1], 1);
    if (idx < SCAP) { w.s1[idx] = r; w.slot[r] = idx; }
    else            { w.slot[r] = -3; }
  }
}

__device__ __forceinline__ void hit_tgt(WsPtrs& w, const int* eiraw,
                                        const long long* ell, bool is64,
                                        const float* ew, long e) {
  int r = is64 ? (int)ell[e] : eiraw[e];
  int i1 = atomicAdd(&w.cnt[0], 1);
  if (i1 < L1CAP) { w.l1r[i1] = r; w.l1w[i1] = ew[e]; }
  reg_s1(w, r);
}

// K2: vectorized col scan; emit int32 wscol; collect edges into tgt; build S1
__global__ void kpassA(WsPtrs w, const int* eiraw, const float* ew, int E) {
  const int tgt = w.cnt[4];
  const bool is64 = w.cnt[3] != 0;
  const long long* ell = (const long long*)eiraw;
  int g = blockIdx.x * blockDim.x + threadIdx.x;
  int gs = gridDim.x * blockDim.x;
  int nv = E >> 1;
  int2* wc2 = (int2*)w.wscol;
  for (int j = g; j < nv; j += gs) {
    int c0, c1;
    if (is64) { longlong2 cc = ((const longlong2*)(ell + E))[j]; c0 = (int)cc.x; c1 = (int)cc.y; }
    else      { int2 cc = ((const int2*)(eiraw + E))[j]; c0 = cc.x; c1 = cc.y; }
    wc2[j] = make_int2(c0, c1);
    if (c0 == tgt) hit_tgt(w, eiraw, ell, is64, ew, 2L * j);
    if (c1 == tgt) hit_tgt(w, eiraw, ell, is64, ew, 2L * j + 1);
  }
  for (long e = 2L * nv + g; e < E; e += gs) {
    int c = is64 ? (int)ell[E + e] : eiraw[E + e];
    w.wscol[e] = c;
    if (c == tgt) hit_tgt(w, eiraw, ell, is64, ew, e);
  }
  if (g == 0) {  // tgt's self loop (weight 1.0)
    int i1 = atomicAdd(&w.cnt[0], 1);
    if (i1 < L1CAP) { w.l1r[i1] = tgt; w.l1w[i1] = 1.0f; }
    reg_s1(w, tgt);
  }
}

// K3: zero used h1 rows; S1 self loops; scan wscol (int4) for edges into S1
__global__ void kpassB(WsPtrs w, const int* eiraw, const float* ew, int E) {
  const bool is64 = w.cnt[3] != 0;
  const long long* ell = (const long long*)eiraw;
  int g = blockIdx.x * blockDim.x + threadIdx.x;
  int gs = gridDim.x * blockDim.x;
  int ns = w.cnt[1]; if (ns > SCAP) ns = SCAP;
  for (int j = g; j < ns * HID; j += gs) w.h1[j] = 0.f;   // only used rows
  for (int j = g; j < ns; j += gs) {   // S1 self loops
    int idx = atomicAdd(&w.cnt[2], 1);
    if (idx < L2CAP) { w.l2r[idx] = w.s1[j]; w.l2s[idx] = j; w.l2w[idx] = 1.0f; }
  }
  const int4* c4 = (const int4*)w.wscol;
  int nv = E >> 2;
  for (int j = g; j < nv; j += gs) {
    int4 v = c4[j];
    #pragma unroll
    for (int t = 0; t < 4; ++t) {
      int c = (t == 0) ? v.x : (t == 1) ? v.y : (t == 2) ? v.z : v.w;
      int s = w.slot[c];
      if (s >= 0) {
        long e = 4L * j + t;
        int r = is64 ? (int)ell[e] : eiraw[e];
        int idx = atomicAdd(&w.cnt[2], 1);
        if (idx < L2CAP) { w.l2r[idx] = r; w.l2s[idx] = s; w.l2w[idx] = ew[e]; }
        int old = atomicCAS(&w.slot[r], -1, -3);
        if (old == -1) w.deg[r] = 1.0f;
      }
    }
  }
  for (long e = 4L * nv + g; e < E; e += gs) {
    int c = w.wscol[e];
    int s = w.slot[c];
    if (s >= 0) {
      int r = is64 ? (int)ell[e] : eiraw[e];
      int idx = atomicAdd(&w.cnt[2], 1);
      if (idx < L2CAP) { w.l2r[idx] = r; w.l2s[idx] = s; w.l2w[idx] = ew[e]; }
      int old = atomicCAS(&w.slot[r], -1, -3);
      if (old == -1) w.deg[r] = 1.0f;
    }
  }
}

// K4: deg accumulation for marked nodes only (~5K atomics)
__global__ void kpassC(WsPtrs w, const float* ew, int E) {
  int g = blockIdx.x * blockDim.x + threadIdx.x;
  int gs = gridDim.x * blockDim.x;
  const int4* c4 = (const int4*)w.wscol;
  int nv = E >> 2;
  for (int j = g; j < nv; j += gs) {
    int4 v = c4[j];
    #pragma unroll
    for (int t = 0; t < 4; ++t) {
      int c = (t == 0) ? v.x : (t == 1) ? v.y : (t == 2) ? v.z : v.w;
      if (w.slot[c] != -1) atomicAdd(&w.deg[c], ew[4L * j + t]);
    }
  }
  for (long e = 4L * nv + g; e < E; e += gs) {
    int c = w.wscol[e];
    if (w.slot[c] != -1) atomicAdd(&w.deg[c], ew[e]);
  }
}

// K5: one block per l2 edge: h1[s] += norm * (x[r] @ W1)  (parallel W1 reads)
__global__ void kh1(WsPtrs w, const float* x, const float* W1) {
  __shared__ float xs[INDIM];
  int n = w.cnt[2]; if (n > L2CAP) n = L2CAP;
  int tid = threadIdx.x;
  for (int b = blockIdx.x; b < n; b += gridDim.x) {
    int r = w.l2r[b], s = w.l2s[b];
    float wt = w.l2w[b];
    int c = w.s1[s];
    float norm = rsqrtf(w.deg[r]) * wt * rsqrtf(w.deg[c]);
    if (tid < INDIM) xs[tid] = x[(long)r * INDIM + tid];
    __syncthreads();
    float acc = 0.f;
    #pragma unroll 8
    for (int k = 0; k < INDIM; ++k) acc += xs[k] * W1[k * HID + tid];
    atomicAdd(&w.h1[s * HID + tid], norm * acc);
    __syncthreads();
  }
}

// K6: 16 blocks x 256. Each block redundantly computes
//   u = sum_b norm_b * relu(h1[s_b]+b1)   (linearity: h2 = u @ W2)
//   feat = [relu(u@W2 + b2)*m | wt | mut | delta | pe]
// then its 32-output slice of f1 = relu(feat @ Wh1 + bh1).
__global__ void khead1(WsPtrs w, const float* b1, const float* W2, const float* b2,
                       const float* mask, const int* wtI_, const int* mutI_,
                       const float* aa, const float* pemb,
                       const float* Wh1, const float* bh1) {
  __shared__ float u[HID];
  __shared__ float feat[480];
  __shared__ float pp[256];
  __shared__ float nrm[256];
  __shared__ int   sidx[256];
  int t = threadIdx.x;
  int tgt = w.cnt[4];
  float dti = rsqrtf(w.deg[tgt]);
  int n1 = w.cnt[0]; if (n1 > 256) n1 = 256;
  if (t < n1) {
    int v = w.l1r[t];
    sidx[t] = w.slot[v];
    nrm[t] = rsqrtf(w.deg[v]) * w.l1w[t] * dti;
  }
  __syncthreads();
  float acc = 0.f;
  float bt = b1[t];
  for (int b = 0; b < n1; ++b) {
    int s = sidx[b];
    if (s >= 0) acc += nrm[b] * fmaxf(w.h1[s * HID + t] + bt, 0.f);
  }
  u[t] = acc;
  __syncthreads();
  float h2 = 0.f;
  #pragma unroll 8
  for (int k = 0; k < HID; ++k) h2 += u[k] * W2[k * HID + t];
  feat[t] = fmaxf(h2 + b2[t], 0.f) * mask[tgt];
  if (t < 64) {
    int wi = wtI_[0], mi = mutI_[0];   // small non-negative; low word ok i32/i64
    float a = aa[wi * 64 + t];
    float b = aa[mi * 64 + t];
    feat[256 + t] = a; feat[320 + t] = b; feat[384 + t] = b - a;
  }
  int pos = tgt; if (pos > 511) pos = 511; if (pos < 0) pos = 0;
  if (t < 32) feat[448 + t] = pemb[pos * 32 + t];
  __syncthreads();
  // f1 slice: outputs [32*blk, 32*blk+32), 8-way split-K (480 = 8*60)
  {
    int o = 32 * blockIdx.x + (t & 31);
    int k0 = (t >> 5) * 60;
    float v = 0.f;
    #pragma unroll 4
    for (int k = k0; k < k0 + 60; ++k) v += feat[k] * Wh1[k * 512 + o];
    pp[t] = v;
  }
  __syncthreads();
  if (t < 32) {
    int o = 32 * blockIdx.x + t;
    float s = bh1[o];
    #pragma unroll
    for (int p = 0; p < 8; ++p) s += pp[p * 32 + t];
    w.f1[o] = fmaxf(s, 0.f);
  }
}

// K7: 1 block x 1024: f2 = relu(f1 @ Wh2 + bh2); out = f2 . Wh3 + bh3
__global__ void __launch_bounds__(1024) khead2(WsPtrs w, const float* Wh2,
                                               const float* bh2, const float* Wh3,
                                               const float* bh3, float* out) {
  __shared__ float f1s[512];
  __shared__ float pp[1024];
  __shared__ float f2[128];
  int t = threadIdx.x;
  if (t < 512) f1s[t] = w.f1[t];
  __syncthreads();
  {
    int o = t & 127;
    int k0 = (t >> 7) * 64;
    float v = 0.f;
    #pragma unroll 4
    for (int k = k0; k < k0 + 64; ++k) v += f1s[k] * Wh2[k * 128 + o];
    pp[t] = v;
  }
  __syncthreads();
  if (t < 128) {
    float s = bh2[t];
    #pragma unroll
    for (int j = 0; j < 8; ++j) s += pp[j * 128 + t];
    f2[t] = fmaxf(s, 0.f) * Wh3[t];
  }
  __syncthreads();
  if (t == 0) {
    float s = bh3[0];
    for (int k = 0; k < 128; ++k) s += f2[k];
    out[0] = s;
  }
}

extern "C" void kernel_launch(void* const* d_in, const int* in_sizes, int n_in,
                              void* d_out, int out_size, void* d_ws, size_t ws_size,
                              hipStream_t stream) {
  const float* x    = (const float*)d_in[0];
  const int*   ei   = (const int*)d_in[1];
  const float* ew   = (const float*)d_in[2];
  const float* mask = (const float*)d_in[3];
  const int*   wtI  = (const int*)d_in[4];
  const int*   mutI = (const int*)d_in[5];
  const float* W1   = (const float*)d_in[6];
  const float* b1   = (const float*)d_in[7];
  const float* W2   = (const float*)d_in[8];
  const float* b2   = (const float*)d_in[9];
  const float* aa   = (const float*)d_in[10];
  const float* pemb = (const float*)d_in[11];
  const float* Wh1  = (const float*)d_in[12];
  const float* bh1  = (const float*)d_in[13];
  const float* Wh2  = (const float*)d_in[14];
  const float* bh2  = (const float*)d_in[15];
  const float* Wh3  = (const float*)d_in[16];
  const float* bh3  = (const float*)d_in[17];
  float* out = (float*)d_out;
  const int N = in_sizes[3];   // mut_mask length
  const int E = in_sizes[2];   // edge_weight length

  char* q = (char*)d_ws;
  auto take = [&](size_t bytes) -> char* {
    char* r = q; q += (bytes + 255) & ~(size_t)255; return r;
  };
  WsPtrs w;
  w.cnt   = (int*)take(64);
  w.deg   = (float*)take((size_t)N * 4);
  w.slot  = (int*)take((size_t)N * 4);
  w.s1    = (int*)take(SCAP * 4);
  w.l1r   = (int*)take(L1CAP * 4);
  w.l1w   = (float*)take(L1CAP * 4);
  w.l2r   = (int*)take(L2CAP * 4);
  w.l2s   = (int*)take(L2CAP * 4);
  w.l2w   = (float*)take(L2CAP * 4);
  w.h1    = (float*)take((size_t)SCAP * HID * 4);
  w.f1    = (float*)take(512 * 4);
  w.wscol = (int*)take((size_t)E * 4);

  kinit  <<<256, 256, 0, stream>>>(w, ei, mask, N, E);
  kpassA <<<1024, 256, 0, stream>>>(w, ei, ew, E);
  kpassB <<<1024, 256, 0, stream>>>(w, ei, ew, E);
  kpassC <<<1024, 256, 0, stream>>>(w, ew, E);
  kh1    <<<512, 256, 0, stream>>>(w, x, W1);
  khead1 <<<16, 256, 0, stream>>>(w, b1, W2, b2, mask, wtI, mutI, aa, pemb, Wh1, bh1);
  khead2 <<<1, 1024, 0, stream>>>(w, Wh2, bh2, Wh3, bh3, out);
}